// Round 11
// baseline (487.793 us; speedup 1.0000x reference)
//
#include <hip/hip_runtime.h>
#include <cstdint>

// ---------------------------------------------------------------------------
// GAT x3 (2-head 64d, 2-head 64d, 1-head 40d) + BN/ReLU between layers.
// Round 18:
//   - gather2 grid-stride (exactly 2048 blocks = 8/CU co-resident): each wave
//     loops ~12 nodes; BN stats accumulated in REGISTERS across the loop
//     (column = sub*8+k is loop-invariant), one LDS reduce + 1KB atomic row
//     per block at the end. Stats write traffic 25.6MB -> 2MB per layer.
//     (R10's 8-node-serial failed from drain imbalance at 3125 long blocks;
//     2048 co-resident grid-stride blocks all finish within one iteration.)
//   - Everything else identical to R17 (reg-scan, bf16 agg, padded L2 rows).
// ---------------------------------------------------------------------------

#define TILE_A 8192
#define BCAP 10240
#define NSLICE 32
#define MPAD 40960  // 1024 threads x 40 ints (>= nbuck*nbA = 38416)
#define G2_BLOCKS 2048

typedef __attribute__((ext_vector_type(8))) short bf16x8v;
typedef __attribute__((ext_vector_type(4))) float f32x4v;
typedef __attribute__((ext_vector_type(2))) float f32x2;
typedef __attribute__((ext_vector_type(2))) unsigned int u32x2;
typedef __attribute__((ext_vector_type(4))) unsigned int u32x4;

__device__ __forceinline__ uint32_t bf16x2_pack(float a, float b) {
  uint32_t ua = __float_as_uint(a);
  ua = (ua + 0x7FFF + ((ua >> 16) & 1)) >> 16;
  uint32_t ub = __float_as_uint(b);
  ub = (ub + 0x7FFF + ((ub >> 16) & 1)) >> 16;
  return ua | (ub << 16);
}
__device__ __forceinline__ uint16_t bf16_1(float a) {
  uint32_t ua = __float_as_uint(a);
  return (uint16_t)((ua + 0x7FFF + ((ua >> 16) & 1)) >> 16);
}
__device__ __forceinline__ f32x2 up2(uint32_t u) {
  u32x2 t = {u << 16, u & 0xFFFF0000u};
  return __builtin_bit_cast(f32x2, t);
}

// ---- CSR build: two-level counting sort (512-node buckets) ----
// Also performs weight transposes + stats zeroing + counts-pad zeroing.

__global__ __launch_bounds__(256) void bucket_hist_k(const int* __restrict__ dst,
                                                     int* __restrict__ counts,
                                                     int E, int nbA, int nbuck,
                                                     const float* __restrict__ w0,
                                                     const float* __restrict__ w1,
                                                     const float* __restrict__ w2,
                                                     uint16_t* __restrict__ wt0,
                                                     uint16_t* __restrict__ wt1,
                                                     uint16_t* __restrict__ wt2,
                                                     float* __restrict__ stats) {
  __shared__ int hist[256];
  int t = threadIdx.x;
  hist[t] = 0;
  __syncthreads();
  int lo = blockIdx.x * TILE_A;
  int hi = min(lo + TILE_A, E);
  for (int i = lo + t; i < hi; i += 256) atomicAdd(&hist[dst[i] >> 9], 1);
  __syncthreads();
  if (t < nbuck) counts[t * nbA + blockIdx.x] = hist[t];

  // fused prep (single predicated pass; grid = 196*256 = 50176 threads)
  int gtid = blockIdx.x * 256 + t;
  if (gtid < 16384) {
    int n = gtid >> 7, k = gtid & 127;
    wt0[gtid] = bf16_1(w0[k * 128 + n]);
    wt1[gtid] = bf16_1(w1[k * 128 + n]);
  }
  if (gtid < 48 * 128) {
    int n = gtid >> 7, k = gtid & 127;
    wt2[gtid] = bf16_1((n < 40) ? w2[k * 40 + n] : 0.f);
  }
  if (gtid < 2 * NSLICE * 256) stats[gtid] = 0.f;
  // zero the counts pad [M, MPAD)
  int M = nbuck * nbA;
  int pidx = M + gtid;
  if (pidx < MPAD) counts[pidx] = 0;
}

// Register-resident exclusive scan of counts[0..MPAD): 1024 threads x 40 ints
// as 10 unrolled int4 loads (pipelined), write-back from registers.
__global__ __launch_bounds__(1024) void scan_counts_k(int* __restrict__ counts,
                                                      int* __restrict__ rowptr,
                                                      int* __restrict__ csr_src,
                                                      int N, int E) {
  __shared__ int part[1024];
  int t = threadIdx.x;
  int base = t * 40;
  int4 v[10];
#pragma unroll
  for (int k = 0; k < 10; ++k) v[k] = *(const int4*)(counts + base + k * 4);
  int s = 0;
#pragma unroll
  for (int k = 0; k < 10; ++k) s += (v[k].x + v[k].y) + (v[k].z + v[k].w);
  part[t] = s;
  __syncthreads();
  for (int off = 1; off < 1024; off <<= 1) {
    int u = (t >= off) ? part[t - off] : 0;
    __syncthreads();
    part[t] += u;
    __syncthreads();
  }
  int run = (t == 0) ? 0 : part[t - 1];
#pragma unroll
  for (int k = 0; k < 10; ++k) {
    int4 w;
    w.x = run; run += v[k].x;
    w.y = run; run += v[k].y;
    w.z = run; run += v[k].z;
    w.w = run; run += v[k].w;
    *(int4*)(counts + base + k * 4) = w;
  }
  if (t == 0) rowptr[N] = E;
  if (t < 64) csr_src[E + t] = 0;  // zero the idle-lane pad
}

__global__ __launch_bounds__(256) void bucket_scatter_k(const int* __restrict__ src,
                                                        const int* __restrict__ dst,
                                                        const int* __restrict__ counts,
                                                        uint32_t* __restrict__ barr,
                                                        int E, int nbA, int nbuck) {
  __shared__ int cur[256];
  int t = threadIdx.x;
  if (t < nbuck) cur[t] = counts[t * nbA + blockIdx.x];
  __syncthreads();
  int lo = blockIdx.x * TILE_A;
  int hi = min(lo + TILE_A, E);
  for (int i = lo + t; i < hi; i += 256) {
    int d = dst[i];
    int b = d >> 9;
    int pos = atomicAdd(&cur[b], 1);
    barr[pos] = ((uint32_t)(d & 511) << 17) | (uint32_t)src[i];
  }
}

__global__ __launch_bounds__(256) void bucket_sort_k(const uint32_t* __restrict__ barr,
                                                     const int* __restrict__ counts,
                                                     int* __restrict__ rowptr,
                                                     int* __restrict__ csr_src,
                                                     int nbA, int nbuck, int N, int E) {
  __shared__ uint32_t ebuf[BCAP];
  __shared__ int hist[512];
  __shared__ int cur[512];
  int b = blockIdx.x;
  int t = threadIdx.x;
  int start = counts[b * nbA];
  int end = (b == nbuck - 1) ? E : counts[(b + 1) * nbA];
  int cnt = end - start;
  if (cnt > BCAP) cnt = BCAP;
  for (int i = t; i < cnt; i += 256) ebuf[i] = barr[start + i];
  for (int i = t; i < 512; i += 256) hist[i] = 0;
  __syncthreads();
  for (int i = t; i < cnt; i += 256) atomicAdd(&hist[ebuf[i] >> 17], 1);
  __syncthreads();
  if (t < 64) {
    int v[8];
    int s = 0;
#pragma unroll
    for (int k = 0; k < 8; ++k) { v[k] = hist[t * 8 + k]; s += v[k]; }
    int inc = s;
#pragma unroll
    for (int off = 1; off < 64; off <<= 1) {
      int u = __shfl_up(inc, off, 64);
      if (t >= off) inc += u;
    }
    int run = inc - s;
#pragma unroll
    for (int k = 0; k < 8; ++k) { hist[t * 8 + k] = run; run += v[k]; }
  }
  __syncthreads();
  int node0 = b << 9;
  int lim = N - node0;
  if (lim > 512) lim = 512;
  for (int i = t; i < 512; i += 256) {
    cur[i] = hist[i];
    if (i < lim) rowptr[node0 + i] = start + hist[i];
  }
  __syncthreads();
  for (int i = t; i < cnt; i += 256) {
    uint32_t e = ebuf[i];
    int ld = e >> 17;
    int pos = atomicAdd(&cur[ld], 1);
    csr_src[start + pos] = (int)(e & 0x1FFFFu);
  }
}

// ---- per-layer kernels ----

// H(bf16) = norm(X) @ W via MFMA. NORM=false: X is f32 (layer 0).
// NORM=true: X is bf16 (agg buffer), BN+ReLU applied during staging.
// H staged through LDS -> coalesced uint4 stores; als/ald from LDS rows.
// stats is a 32-slice partial-sum buffer [NSLICE][256] (sum | sumsq).
template <bool NORM, int NT, int HEADS>
__global__ __launch_bounds__(256) void gemm_mfma_k(const float* __restrict__ X,
                                                   const uint16_t* __restrict__ WT,
                                                   uint16_t* __restrict__ Hout,
                                                   const float* __restrict__ stats,
                                                   const float* __restrict__ g,
                                                   const float* __restrict__ beta,
                                                   const float* __restrict__ asrc,
                                                   const float* __restrict__ adst,
                                                   float* __restrict__ als,
                                                   float* __restrict__ ald,
                                                   int nrows, int cols, int stride) {
  __shared__ short A_lds[64 * 136];
  __shared__ float sscale[128];
  __shared__ float sbias[128];
  __shared__ float sasrc[128];
  __shared__ float sadst[128];
  __shared__ float part_s[64][4];
  __shared__ float part_d[64][4];
  int tid = threadIdx.x;
  if (tid < 128) {
    sasrc[tid] = (tid < cols) ? asrc[tid] : 0.f;
    sadst[tid] = (tid < cols) ? adst[tid] : 0.f;
  }
  if (NORM && tid < 128) {
    float s = 0.f, s2 = 0.f;
#pragma unroll 4
    for (int sl = 0; sl < NSLICE; ++sl) {
      s += stats[sl * 256 + tid];
      s2 += stats[sl * 256 + 128 + tid];
    }
    float invn = 1.0f / (float)nrows;
    float mean = s * invn;
    float var = s2 * invn - mean * mean;
    float sc = g[tid] * rsqrtf(var + 1e-5f);
    sscale[tid] = sc;
    sbias[tid] = beta[tid] - mean * sc;
  }
  if (NORM) __syncthreads();
  int row0 = blockIdx.x * 64;
#pragma unroll
  for (int it = 0; it < 8; ++it) {
    int e = (tid + it * 256) * 4;
    int row = e >> 7;
    int kh = e & 127;
    int gr = row0 + row;
    uint2 pk;
    if (NORM) {
      // bf16 input (agg): uint2 = 4 bf16 dims
      u32x2 uv = {0u, 0u};
      if (gr < nrows)
        uv = __builtin_nontemporal_load(
            (const u32x2*)((const uint32_t*)X + (size_t)gr * 64 + (kh >> 1)));
      f32x2 p0 = up2(uv[0]);
      f32x2 p1 = up2(uv[1]);
      float v0 = fmaxf(fmaf(p0.x, sscale[kh + 0], sbias[kh + 0]), 0.f);
      float v1 = fmaxf(fmaf(p0.y, sscale[kh + 1], sbias[kh + 1]), 0.f);
      float v2 = fmaxf(fmaf(p1.x, sscale[kh + 2], sbias[kh + 2]), 0.f);
      float v3 = fmaxf(fmaf(p1.y, sscale[kh + 3], sbias[kh + 3]), 0.f);
      pk.x = bf16x2_pack(v0, v1);
      pk.y = bf16x2_pack(v2, v3);
    } else {
      f32x4v xv = {0.f, 0.f, 0.f, 0.f};
      if (gr < nrows)
        xv = __builtin_nontemporal_load((const f32x4v*)(X + (size_t)gr * 128 + kh));
      pk.x = bf16x2_pack(xv[0], xv[1]);
      pk.y = bf16x2_pack(xv[2], xv[3]);
    }
    *(uint2*)(&A_lds[row * 136 + kh]) = pk;
  }
  __syncthreads();

  int wave = tid >> 6;
  int lane = tid & 63;
  int m = lane & 15;
  int quad = lane >> 4;

  bf16x8v afrag[4];
#pragma unroll
  for (int kc = 0; kc < 4; ++kc)
    afrag[kc] = *(const bf16x8v*)(&A_lds[(wave * 16 + m) * 136 + kc * 32 + quad * 8]);

  f32x4v acc[NT];
#pragma unroll
  for (int t = 0; t < NT; ++t) acc[t] = (f32x4v){0.f, 0.f, 0.f, 0.f};

#pragma unroll
  for (int t = 0; t < NT; ++t) {
#pragma unroll
    for (int kc = 0; kc < 4; ++kc) {
      bf16x8v bfrag = *(const bf16x8v*)(WT + ((t * 16 + m) * 128 + kc * 32 + quad * 8));
      acc[t] = __builtin_amdgcn_mfma_f32_16x16x32_bf16(afrag[kc], bfrag, acc[t], 0, 0, 0);
    }
  }

  // ---- stage H (bf16) into LDS: reuse A_lds ----
  __syncthreads();
  if (NT == 3) {
    // zero cols 48..63 so the readback rows and als chunk-1 are clean
    for (int i = tid; i < 64 * 16; i += 256) {
      int row = i >> 4, c = 48 + (i & 15);
      A_lds[row * 136 + c] = 0;
    }
  }
#pragma unroll
  for (int t = 0; t < NT; ++t) {
    int col = t * 16 + m;
#pragma unroll
    for (int r = 0; r < 4; ++r) {
      int row = wave * 16 + quad * 4 + r;
      A_lds[row * 136 + col] = (short)bf16_1(acc[t][r]);
    }
  }
  __syncthreads();

  // ---- als/ald: 32-col chunk partials, NCH chunks per row ----
  constexpr int NCH = (NT == 8) ? 4 : 2;
  if (tid < 64 * NCH) {
    int row = tid / NCH, ch = tid % NCH;
    float ps = 0.f, pd = 0.f;
#pragma unroll
    for (int q = 0; q < 4; ++q) {
      bf16x8v hv = *(const bf16x8v*)(&A_lds[row * 136 + ch * 32 + q * 8]);
#pragma unroll
      for (int e = 0; e < 8; ++e) {
        float hf = __uint_as_float(((uint32_t)(unsigned short)hv[e]) << 16);
        int c = ch * 32 + q * 8 + e;
        ps = fmaf(hf, sasrc[c], ps);
        pd = fmaf(hf, sadst[c], pd);
      }
    }
    part_s[row][ch] = ps;
    part_d[row][ch] = pd;
  }

  // ---- coalesced H stores (uint4 = 8 cols) ----
  int c8 = stride >> 3;
  int total = 64 * c8;
  for (int idx = tid; idx < total; idx += 256) {
    int row = idx / c8;
    int cc = (idx - row * c8) * 8;
    int grow = row0 + row;
    if (grow < nrows) {
      u32x4 v = *(const u32x4*)(&A_lds[row * 136 + cc]);
      *(u32x4*)(Hout + (size_t)grow * stride + cc) = v;
    }
  }

  __syncthreads();
  if (tid < 64) {
    int grow = row0 + tid;
    if (grow < nrows) {
      if (HEADS == 2) {
        float s0 = part_s[tid][0] + part_s[tid][1];
        float s1 = part_s[tid][2] + part_s[tid][3];
        float d0 = part_d[tid][0] + part_d[tid][1];
        float d1 = part_d[tid][2] + part_d[tid][3];
        ((float2*)als)[grow] = make_float2(s0, s1);
        ((float2*)ald)[grow] = make_float2(d0, d1);
      } else {
        als[grow] = part_s[tid][0] + part_s[tid][1];
        ald[grow] = part_d[tid][0] + part_d[tid][1];
      }
    }
  }
}

// 2 heads x 64 dims, h bf16 (row = 256B = 16 uint4).
// Grid-stride: G2_BLOCKS co-resident blocks (8/CU); each wave loops over
// nodes (stride 4*G2_BLOCKS). 16 lanes per edge-row, 4 slots. BN stats
// accumulated in registers across the loop (column = sub*8+k is invariant);
// one LDS reduce + one 1KB atomic row per block at the end.
__global__ __launch_bounds__(256) void gat_gather2_k(const int* __restrict__ rowptr,
                                                     const int* __restrict__ csr_src,
                                                     const float* __restrict__ als,
                                                     const float* __restrict__ ald,
                                                     const uint16_t* __restrict__ H,
                                                     const float* __restrict__ bias,
                                                     uint32_t* __restrict__ out,
                                                     float* __restrict__ stats, int N) {
  __shared__ float red[4][256];
  int tid = threadIdx.x;
  int wv = tid >> 6;
  int lane = tid & 63;
  int slot = lane >> 4;        // 0..3: edge slot
  int sub = lane & 15;         // uint4 index within row (dims 8*sub..8*sub+7)
  int head = sub >> 3;
  const char* hbase = (const char*)H;
  uint32_t suboff = (uint32_t)sub << 4;
  bool dlane = (sub & 7) == 0;
  float4 b0 = ((const float4*)bias)[2 * sub];
  float4 b1 = ((const float4*)bias)[2 * sub + 1];
  float ss[8], sq[8];
#pragma unroll
  for (int k = 0; k < 8; ++k) { ss[k] = 0.f; sq[k] = 0.f; }

  int nstride = 4 * G2_BLOCKS;
  for (int n = blockIdx.x * 4 + wv; n < N; n += nstride) {
    int start = rowptr[n];
    int end = rowptr[n + 1];
    float aldn = ald[2 * n + head];
    f32x2 acc0 = {0.f, 0.f}, acc1 = {0.f, 0.f}, acc2 = {0.f, 0.f}, acc3 = {0.f, 0.f};
    float dsum = 0.f;
    int j = start;
    // full 16-edge blocks: no clamping, no predication
    for (; j + 16 <= end; j += 16) {
      int e0 = j + slot;
      int s0 = __builtin_nontemporal_load(csr_src + e0);
      int s1 = __builtin_nontemporal_load(csr_src + e0 + 4);
      int s2 = __builtin_nontemporal_load(csr_src + e0 + 8);
      int s3 = __builtin_nontemporal_load(csr_src + e0 + 12);
      uint4 u0 = *(const uint4*)(hbase + (((uint32_t)s0 << 8) + suboff));
      uint4 u1 = *(const uint4*)(hbase + (((uint32_t)s1 << 8) + suboff));
      uint4 u2 = *(const uint4*)(hbase + (((uint32_t)s2 << 8) + suboff));
      uint4 u3 = *(const uint4*)(hbase + (((uint32_t)s3 << 8) + suboff));
      float l0 = als[2 * s0 + head] + aldn;
      float l1 = als[2 * s1 + head] + aldn;
      float l2 = als[2 * s2 + head] + aldn;
      float l3 = als[2 * s3 + head] + aldn;
      l0 = fmaxf(l0, 0.2f * l0);
      l1 = fmaxf(l1, 0.2f * l1);
      l2 = fmaxf(l2, 0.2f * l2);
      l3 = fmaxf(l3, 0.2f * l3);
      float w0 = __expf(l0), w1 = __expf(l1), w2 = __expf(l2), w3 = __expf(l3);
      if (dlane) dsum += (w0 + w1) + (w2 + w3);
      acc0 += up2(u0.x) * w0;
      acc1 += up2(u0.y) * w0;
      acc2 += up2(u0.z) * w0;
      acc3 += up2(u0.w) * w0;
      acc0 += up2(u1.x) * w1;
      acc1 += up2(u1.y) * w1;
      acc2 += up2(u1.z) * w1;
      acc3 += up2(u1.w) * w1;
      acc0 += up2(u2.x) * w2;
      acc1 += up2(u2.y) * w2;
      acc2 += up2(u2.z) * w2;
      acc3 += up2(u2.w) * w2;
      acc0 += up2(u3.x) * w3;
      acc1 += up2(u3.y) * w3;
      acc2 += up2(u3.z) * w3;
      acc3 += up2(u3.w) * w3;
    }
    // clamped tail (up to 15 edges)
    for (; j < end; j += 8) {
      int last = end - 1;
      int ea = j + slot;
      int eb = ea + 4;
      int sa = csr_src[min(ea, last)];
      int sb = csr_src[min(eb, last)];
      uint4 ua = *(const uint4*)(hbase + (((uint32_t)sa << 8) + suboff));
      uint4 ub = *(const uint4*)(hbase + (((uint32_t)sb << 8) + suboff));
      float la = als[2 * sa + head] + aldn;
      float lb = als[2 * sb + head] + aldn;
      la = fmaxf(la, 0.2f * la);
      lb = fmaxf(lb, 0.2f * lb);
      float wa = (ea < end) ? __expf(la) : 0.f;
      float wb = (eb < end) ? __expf(lb) : 0.f;
      if (dlane) dsum += wa + wb;
      acc0 += up2(ua.x) * wa;
      acc1 += up2(ua.y) * wa;
      acc2 += up2(ua.z) * wa;
      acc3 += up2(ua.w) * wa;
      acc0 += up2(ub.x) * wb;
      acc1 += up2(ub.y) * wb;
      acc2 += up2(ub.z) * wb;
      acc3 += up2(ub.w) * wb;
    }
    // combine the 4 slots
    acc0.x += __shfl_xor(acc0.x, 16, 64); acc0.x += __shfl_xor(acc0.x, 32, 64);
    acc0.y += __shfl_xor(acc0.y, 16, 64); acc0.y += __shfl_xor(acc0.y, 32, 64);
    acc1.x += __shfl_xor(acc1.x, 16, 64); acc1.x += __shfl_xor(acc1.x, 32, 64);
    acc1.y += __shfl_xor(acc1.y, 16, 64); acc1.y += __shfl_xor(acc1.y, 32, 64);
    acc2.x += __shfl_xor(acc2.x, 16, 64); acc2.x += __shfl_xor(acc2.x, 32, 64);
    acc2.y += __shfl_xor(acc2.y, 16, 64); acc2.y += __shfl_xor(acc2.y, 32, 64);
    acc3.x += __shfl_xor(acc3.x, 16, 64); acc3.x += __shfl_xor(acc3.x, 32, 64);
    acc3.y += __shfl_xor(acc3.y, 16, 64); acc3.y += __shfl_xor(acc3.y, 32, 64);
    dsum += __shfl_xor(dsum, 16, 64);
    dsum += __shfl_xor(dsum, 32, 64);
    float denom = __shfl(dsum, head << 3, 64);
    float inv = 1.0f / (denom + 1e-16f);
    if (slot == 0) {
      f32x4v o0, o1;
      o0[0] = acc0.x * inv + b0.x;
      o0[1] = acc0.y * inv + b0.y;
      o0[2] = acc1.x * inv + b0.z;
      o0[3] = acc1.y * inv + b0.w;
      o1[0] = acc2.x * inv + b1.x;
      o1[1] = acc2.y * inv + b1.y;
      o1[2] = acc3.x * inv + b1.z;
      o1[3] = acc3.y * inv + b1.w;
      u32x4 pk;
      pk[0] = bf16x2_pack(o0[0], o0[1]);
      pk[1] = bf16x2_pack(o0[2], o0[3]);
      pk[2] = bf16x2_pack(o1[0], o1[1]);
      pk[3] = bf16x2_pack(o1[2], o1[3]);
      __builtin_nontemporal_store(pk, (u32x4*)(out + (size_t)n * 64 + 4 * sub));
      ss[0] += o0[0]; sq[0] += o0[0] * o0[0];
      ss[1] += o0[1]; sq[1] += o0[1] * o0[1];
      ss[2] += o0[2]; sq[2] += o0[2] * o0[2];
      ss[3] += o0[3]; sq[3] += o0[3] * o0[3];
      ss[4] += o1[0]; sq[4] += o1[0] * o1[0];
      ss[5] += o1[1]; sq[5] += o1[1] * o1[1];
      ss[6] += o1[2]; sq[6] += o1[2] * o1[2];
      ss[7] += o1[3]; sq[7] += o1[3] * o1[3];
    }
  }

  // ---- stats epilogue: register -> LDS -> one atomic row per block ----
  if (slot == 0) {
    int c = sub << 3;
#pragma unroll
    for (int k = 0; k < 8; ++k) {
      red[wv][c + k] = ss[k];
      red[wv][128 + c + k] = sq[k];
    }
  }
  __syncthreads();
  float v = red[0][tid] + red[1][tid] + red[2][tid] + red[3][tid];
  atomicAdd(&stats[((blockIdx.x & (NSLICE - 1)) << 8) + tid], v);
}

// 1 head x 40 dims, h bf16 padded to 128B rows (5 uint4 used). 5 lanes per
// edge-row, 12 slots (lanes 60-63 idle). Unclamped 12-edge main loop
// (granularity matches mean degree 16) + clamped 12-edge tail.
__global__ __launch_bounds__(256) void gat_gather1_k(const int* __restrict__ rowptr,
                                                     const int* __restrict__ csr_src,
                                                     const float* __restrict__ als,
                                                     const float* __restrict__ ald,
                                                     const uint16_t* __restrict__ H,
                                                     const float* __restrict__ bias,
                                                     float* __restrict__ out, int N) {
  int n = blockIdx.x * 4 + (threadIdx.x >> 6);
  if (n >= N) return;
  int lane = threadIdx.x & 63;
  int slot = lane / 5;            // 0..11 active, 12 = idle (lanes 60-63)
  int d = lane - slot * 5;        // uint4 index within row (dims 8d..8d+7)
  bool act = slot < 12;
  int start = rowptr[n], end = rowptr[n + 1];
  float aldn = ald[n];
  const char* hbase = (const char*)H;
  uint32_t doff = (uint32_t)d << 4;
  f32x2 a0 = {0.f, 0.f}, a1 = {0.f, 0.f}, a2 = {0.f, 0.f}, a3 = {0.f, 0.f};
  float dsum = 0.f;
  int j = start;
  // unclamped main: active lanes always in-range; idle lanes read the
  // zero-padded csr_src[end..] (safe) with w forced 0.
  for (; j + 12 <= end; j += 12) {
    int e0 = j + slot;
    int s0 = __builtin_nontemporal_load(csr_src + e0);
    uint4 u0 = *(const uint4*)(hbase + (((uint32_t)s0 << 7) + doff));
    float l0 = als[s0] + aldn;
    l0 = fmaxf(l0, 0.2f * l0);
    float w0 = act ? __expf(l0) : 0.f;
    if (d == 0) dsum += w0;
    a0 += up2(u0.x) * w0;
    a1 += up2(u0.y) * w0;
    a2 += up2(u0.z) * w0;
    a3 += up2(u0.w) * w0;
  }
  // clamped tail (up to 11 edges)
  for (; j < end; j += 12) {
    int last = end - 1;
    int e0 = j + slot;
    int s0 = __builtin_nontemporal_load(csr_src + min(e0, last));
    uint4 u0 = *(const uint4*)(hbase + (((uint32_t)s0 << 7) + doff));
    float l0 = als[s0] + aldn;
    l0 = fmaxf(l0, 0.2f * l0);
    float w0 = (act && e0 < end) ? __expf(l0) : 0.f;
    if (d == 0) dsum += w0;
    a0 += up2(u0.x) * w0;
    a1 += up2(u0.y) * w0;
    a2 += up2(u0.z) * w0;
    a3 += up2(u0.w) * w0;
  }
  // fold 12 slots -> 1 (same d): +6 slots, +3 slots, then +1,+2 slots
#define FOLD2(off)                                        \
  a0.x += __shfl(a0.x, (lane + off) & 63, 64);            \
  a0.y += __shfl(a0.y, (lane + off) & 63, 64);            \
  a1.x += __shfl(a1.x, (lane + off) & 63, 64);            \
  a1.y += __shfl(a1.y, (lane + off) & 63, 64);            \
  a2.x += __shfl(a2.x, (lane + off) & 63, 64);            \
  a2.y += __shfl(a2.y, (lane + off) & 63, 64);            \
  a3.x += __shfl(a3.x, (lane + off) & 63, 64);            \
  a3.y += __shfl(a3.y, (lane + off) & 63, 64);
  FOLD2(30)  // slots 0..5 += slots 6..11
  FOLD2(15)  // slots 0..2 += slots 3..5
  {
    float t;
    t = __shfl(a0.x, (lane + 5) & 63, 64) + __shfl(a0.x, (lane + 10) & 63, 64); a0.x += t;
    t = __shfl(a0.y, (lane + 5) & 63, 64) + __shfl(a0.y, (lane + 10) & 63, 64); a0.y += t;
    t = __shfl(a1.x, (lane + 5) & 63, 64) + __shfl(a1.x, (lane + 10) & 63, 64); a1.x += t;
    t = __shfl(a1.y, (lane + 5) & 63, 64) + __shfl(a1.y, (lane + 10) & 63, 64); a1.y += t;
    t = __shfl(a2.x, (lane + 5) & 63, 64) + __shfl(a2.x, (lane + 10) & 63, 64); a2.x += t;
    t = __shfl(a2.y, (lane + 5) & 63, 64) + __shfl(a2.y, (lane + 10) & 63, 64); a2.y += t;
    t = __shfl(a3.x, (lane + 5) & 63, 64) + __shfl(a3.x, (lane + 10) & 63, 64); a3.x += t;
    t = __shfl(a3.y, (lane + 5) & 63, 64) + __shfl(a3.y, (lane + 10) & 63, 64); a3.y += t;
  }
#undef FOLD2
#pragma unroll
  for (int off = 1; off < 64; off <<= 1) dsum += __shfl_xor(dsum, off, 64);
  if (lane < 5) {
    float inv = 1.0f / (dsum + 1e-16f);
    float4 b4a = ((const float4*)bias)[2 * d];
    float4 b4b = ((const float4*)bias)[2 * d + 1];
    f32x4v o0, o1;
    o0[0] = a0.x * inv + b4a.x;
    o0[1] = a0.y * inv + b4a.y;
    o0[2] = a1.x * inv + b4a.z;
    o0[3] = a1.y * inv + b4a.w;
    o1[0] = a2.x * inv + b4b.x;
    o1[1] = a2.y * inv + b4b.y;
    o1[2] = a3.x * inv + b4b.z;
    o1[3] = a3.y * inv + b4b.w;
    float* orow = out + (size_t)n * 40 + 8 * d;
    __builtin_nontemporal_store(o0, (f32x4v*)orow);
    __builtin_nontemporal_store(o1, (f32x4v*)(orow + 4));
  }
}

extern "C" void kernel_launch(void* const* d_in, const int* in_sizes, int n_in,
                              void* d_out, int out_size, void* d_ws, size_t ws_size,
                              hipStream_t stream) {
  const float* x     = (const float*)d_in[0];
  const int*   ei    = (const int*)d_in[1];
  const float* w0    = (const float*)d_in[2];
  const float* asrc0 = (const float*)d_in[3];
  const float* adst0 = (const float*)d_in[4];
  const float* b0    = (const float*)d_in[5];
  const float* g0    = (const float*)d_in[6];
  const float* beta0 = (const float*)d_in[7];
  const float* w1    = (const float*)d_in[8];
  const float* asrc1 = (const float*)d_in[9];
  const float* adst1 = (const float*)d_in[10];
  const float* b1    = (const float*)d_in[11];
  const float* g1    = (const float*)d_in[12];
  const float* beta1 = (const float*)d_in[13];
  const float* w2    = (const float*)d_in[14];
  const float* asrc2 = (const float*)d_in[15];
  const float* adst2 = (const float*)d_in[16];
  const float* b2    = (const float*)d_in[17];

  const int N = in_sizes[0] / 128;   // 100000
  const int E = in_sizes[1] / 2;     // 1600000

  const int nbuck = (N + 511) >> 9;              // 196
  const int nbA = (E + TILE_A - 1) / TILE_A;     // 196

  char* p = (char*)d_ws;
  auto carve = [&](size_t bytes) {
    char* q = p;
    p += (bytes + 255) & ~(size_t)255;
    return q;
  };
  int*      counts  = (int*)carve((size_t)MPAD * 4);      // padded for reg-scan
  int*      rowptr  = (int*)carve((size_t)(N + 1) * 4);
  uint32_t* barr    = (uint32_t*)carve((size_t)E * 4);
  int*      csr_src = (int*)carve((size_t)(E + 64) * 4);  // +64 pad (zeroed)
  float*    als     = (float*)carve((size_t)N * 2 * 4);
  float*    ald     = (float*)carve((size_t)N * 2 * 4);
  float*    stats   = (float*)carve((size_t)2 * NSLICE * 256 * 4);
  uint16_t* wt0     = (uint16_t*)carve(128 * 128 * 2);
  uint16_t* wt1     = (uint16_t*)carve(128 * 128 * 2);
  uint16_t* wt2     = (uint16_t*)carve(48 * 128 * 2);
  uint16_t* hbuf    = (uint16_t*)carve((size_t)N * 128 * 2);  // bf16
  uint32_t* agg     = (uint32_t*)carve((size_t)N * 64 * 4);   // bf16 x2 packed

  float* stats0 = stats;
  float* stats1 = stats + NSLICE * 256;

  const int* esrc = ei;
  const int* edst = ei + E;

  // ---- CSR by dst (fully sorted; shared across all 3 layers) ----
  // hist also does weight transposes + stats zeroing + counts-pad zeroing.
  bucket_hist_k<<<nbA, 256, 0, stream>>>(edst, counts, E, nbA, nbuck,
                                         w0, w1, w2, wt0, wt1, wt2, stats);
  scan_counts_k<<<1, 1024, 0, stream>>>(counts, rowptr, csr_src, N, E);
  bucket_scatter_k<<<nbA, 256, 0, stream>>>(esrc, edst, counts, barr, E, nbA, nbuck);
  bucket_sort_k<<<nbuck, 256, 0, stream>>>(barr, counts, rowptr, csr_src, nbA, nbuck, N, E);

  const int gemm_grid = (N + 63) / 64;
  const int node_grid = (N + 3) / 4;

  // ---- layer 0: GAT(128 -> 64x2) -> (BN+ReLU fused into next gemm) ----
  gemm_mfma_k<false, 8, 2><<<gemm_grid, 256, 0, stream>>>(x, wt0, hbuf, nullptr, nullptr,
                                                          nullptr, asrc0, adst0, als, ald,
                                                          N, 128, 128);
  gat_gather2_k<<<G2_BLOCKS, 256, 0, stream>>>(rowptr, csr_src, als, ald, hbuf,
                                               b0, agg, stats0, N);

  // ---- layer 1 ----
  gemm_mfma_k<true, 8, 2><<<gemm_grid, 256, 0, stream>>>((const float*)agg, wt1, hbuf,
                                                         stats0, g0, beta0,
                                                         asrc1, adst1, als, ald, N, 128, 128);
  gat_gather2_k<<<G2_BLOCKS, 256, 0, stream>>>(rowptr, csr_src, als, ald, hbuf,
                                               b1, agg, stats1, N);

  // ---- layer 2: GAT(128 -> 40, heads=1) -> d_out (H rows padded to 128B) ----
  gemm_mfma_k<true, 3, 1><<<gemm_grid, 256, 0, stream>>>((const float*)agg, wt2, hbuf,
                                                         stats1, g1, beta1,
                                                         asrc2, adst2, als, ald, N, 40, 64);
  gat_gather1_k<<<node_grid, 256, 0, stream>>>(rowptr, csr_src, als, ald, hbuf,
                                               b2, (float*)d_out, N);
}

// Round 12
// 475.025 us; speedup vs baseline: 1.0269x; 1.0269x over previous
//
#include <hip/hip_runtime.h>
#include <cstdint>

// ---------------------------------------------------------------------------
// GAT x3 (2-head 64d, 2-head 64d, 1-head 40d) + BN/ReLU between layers.
// Round 19:
//   - gather2 reverted to R17 per-node form (1 node/wave, node_grid blocks,
//     stats via per-wave LDS + per-block atomic). R18's grid-stride +
//     register-stats dropped occupancy 77->42% (VGPR 48 + block imbalance)
//     and lost 7.7us/dispatch: third confirmation that gather2 needs max
//     wave parallelism; 23MB stats-write savings can't pay for it.
//   - Keeps R17: register-resident scan (the -45us win), bf16 agg, padded
//     layer-2 H rows, fused w_prep/stats-zero, csr pad.
// ---------------------------------------------------------------------------

#define TILE_A 8192
#define BCAP 10240
#define NSLICE 32
#define MPAD 40960  // 1024 threads x 40 ints (>= nbuck*nbA = 38416)

typedef __attribute__((ext_vector_type(8))) short bf16x8v;
typedef __attribute__((ext_vector_type(4))) float f32x4v;
typedef __attribute__((ext_vector_type(2))) float f32x2;
typedef __attribute__((ext_vector_type(2))) unsigned int u32x2;
typedef __attribute__((ext_vector_type(4))) unsigned int u32x4;

__device__ __forceinline__ uint32_t bf16x2_pack(float a, float b) {
  uint32_t ua = __float_as_uint(a);
  ua = (ua + 0x7FFF + ((ua >> 16) & 1)) >> 16;
  uint32_t ub = __float_as_uint(b);
  ub = (ub + 0x7FFF + ((ub >> 16) & 1)) >> 16;
  return ua | (ub << 16);
}
__device__ __forceinline__ uint16_t bf16_1(float a) {
  uint32_t ua = __float_as_uint(a);
  return (uint16_t)((ua + 0x7FFF + ((ua >> 16) & 1)) >> 16);
}
__device__ __forceinline__ f32x2 up2(uint32_t u) {
  u32x2 t = {u << 16, u & 0xFFFF0000u};
  return __builtin_bit_cast(f32x2, t);
}

// ---- CSR build: two-level counting sort (512-node buckets) ----
// Also performs weight transposes + stats zeroing + counts-pad zeroing.

__global__ __launch_bounds__(256) void bucket_hist_k(const int* __restrict__ dst,
                                                     int* __restrict__ counts,
                                                     int E, int nbA, int nbuck,
                                                     const float* __restrict__ w0,
                                                     const float* __restrict__ w1,
                                                     const float* __restrict__ w2,
                                                     uint16_t* __restrict__ wt0,
                                                     uint16_t* __restrict__ wt1,
                                                     uint16_t* __restrict__ wt2,
                                                     float* __restrict__ stats) {
  __shared__ int hist[256];
  int t = threadIdx.x;
  hist[t] = 0;
  __syncthreads();
  int lo = blockIdx.x * TILE_A;
  int hi = min(lo + TILE_A, E);
  for (int i = lo + t; i < hi; i += 256) atomicAdd(&hist[dst[i] >> 9], 1);
  __syncthreads();
  if (t < nbuck) counts[t * nbA + blockIdx.x] = hist[t];

  // fused prep (single predicated pass; grid = 196*256 = 50176 threads)
  int gtid = blockIdx.x * 256 + t;
  if (gtid < 16384) {
    int n = gtid >> 7, k = gtid & 127;
    wt0[gtid] = bf16_1(w0[k * 128 + n]);
    wt1[gtid] = bf16_1(w1[k * 128 + n]);
  }
  if (gtid < 48 * 128) {
    int n = gtid >> 7, k = gtid & 127;
    wt2[gtid] = bf16_1((n < 40) ? w2[k * 40 + n] : 0.f);
  }
  if (gtid < 2 * NSLICE * 256) stats[gtid] = 0.f;
  // zero the counts pad [M, MPAD)
  int M = nbuck * nbA;
  int pidx = M + gtid;
  if (pidx < MPAD) counts[pidx] = 0;
}

// Register-resident exclusive scan of counts[0..MPAD): 1024 threads x 40 ints
// as 10 unrolled int4 loads (pipelined), write-back from registers.
__global__ __launch_bounds__(1024) void scan_counts_k(int* __restrict__ counts,
                                                      int* __restrict__ rowptr,
                                                      int* __restrict__ csr_src,
                                                      int N, int E) {
  __shared__ int part[1024];
  int t = threadIdx.x;
  int base = t * 40;
  int4 v[10];
#pragma unroll
  for (int k = 0; k < 10; ++k) v[k] = *(const int4*)(counts + base + k * 4);
  int s = 0;
#pragma unroll
  for (int k = 0; k < 10; ++k) s += (v[k].x + v[k].y) + (v[k].z + v[k].w);
  part[t] = s;
  __syncthreads();
  for (int off = 1; off < 1024; off <<= 1) {
    int u = (t >= off) ? part[t - off] : 0;
    __syncthreads();
    part[t] += u;
    __syncthreads();
  }
  int run = (t == 0) ? 0 : part[t - 1];
#pragma unroll
  for (int k = 0; k < 10; ++k) {
    int4 w;
    w.x = run; run += v[k].x;
    w.y = run; run += v[k].y;
    w.z = run; run += v[k].z;
    w.w = run; run += v[k].w;
    *(int4*)(counts + base + k * 4) = w;
  }
  if (t == 0) rowptr[N] = E;
  if (t < 64) csr_src[E + t] = 0;  // zero the idle-lane pad
}

__global__ __launch_bounds__(256) void bucket_scatter_k(const int* __restrict__ src,
                                                        const int* __restrict__ dst,
                                                        const int* __restrict__ counts,
                                                        uint32_t* __restrict__ barr,
                                                        int E, int nbA, int nbuck) {
  __shared__ int cur[256];
  int t = threadIdx.x;
  if (t < nbuck) cur[t] = counts[t * nbA + blockIdx.x];
  __syncthreads();
  int lo = blockIdx.x * TILE_A;
  int hi = min(lo + TILE_A, E);
  for (int i = lo + t; i < hi; i += 256) {
    int d = dst[i];
    int b = d >> 9;
    int pos = atomicAdd(&cur[b], 1);
    barr[pos] = ((uint32_t)(d & 511) << 17) | (uint32_t)src[i];
  }
}

__global__ __launch_bounds__(256) void bucket_sort_k(const uint32_t* __restrict__ barr,
                                                     const int* __restrict__ counts,
                                                     int* __restrict__ rowptr,
                                                     int* __restrict__ csr_src,
                                                     int nbA, int nbuck, int N, int E) {
  __shared__ uint32_t ebuf[BCAP];
  __shared__ int hist[512];
  __shared__ int cur[512];
  int b = blockIdx.x;
  int t = threadIdx.x;
  int start = counts[b * nbA];
  int end = (b == nbuck - 1) ? E : counts[(b + 1) * nbA];
  int cnt = end - start;
  if (cnt > BCAP) cnt = BCAP;
  for (int i = t; i < cnt; i += 256) ebuf[i] = barr[start + i];
  for (int i = t; i < 512; i += 256) hist[i] = 0;
  __syncthreads();
  for (int i = t; i < cnt; i += 256) atomicAdd(&hist[ebuf[i] >> 17], 1);
  __syncthreads();
  if (t < 64) {
    int v[8];
    int s = 0;
#pragma unroll
    for (int k = 0; k < 8; ++k) { v[k] = hist[t * 8 + k]; s += v[k]; }
    int inc = s;
#pragma unroll
    for (int off = 1; off < 64; off <<= 1) {
      int u = __shfl_up(inc, off, 64);
      if (t >= off) inc += u;
    }
    int run = inc - s;
#pragma unroll
    for (int k = 0; k < 8; ++k) { hist[t * 8 + k] = run; run += v[k]; }
  }
  __syncthreads();
  int node0 = b << 9;
  int lim = N - node0;
  if (lim > 512) lim = 512;
  for (int i = t; i < 512; i += 256) {
    cur[i] = hist[i];
    if (i < lim) rowptr[node0 + i] = start + hist[i];
  }
  __syncthreads();
  for (int i = t; i < cnt; i += 256) {
    uint32_t e = ebuf[i];
    int ld = e >> 17;
    int pos = atomicAdd(&cur[ld], 1);
    csr_src[start + pos] = (int)(e & 0x1FFFFu);
  }
}

// ---- per-layer kernels ----

// H(bf16) = norm(X) @ W via MFMA. NORM=false: X is f32 (layer 0).
// NORM=true: X is bf16 (agg buffer), BN+ReLU applied during staging.
// H staged through LDS -> coalesced uint4 stores; als/ald from LDS rows.
// stats is a 32-slice partial-sum buffer [NSLICE][256] (sum | sumsq).
template <bool NORM, int NT, int HEADS>
__global__ __launch_bounds__(256) void gemm_mfma_k(const float* __restrict__ X,
                                                   const uint16_t* __restrict__ WT,
                                                   uint16_t* __restrict__ Hout,
                                                   const float* __restrict__ stats,
                                                   const float* __restrict__ g,
                                                   const float* __restrict__ beta,
                                                   const float* __restrict__ asrc,
                                                   const float* __restrict__ adst,
                                                   float* __restrict__ als,
                                                   float* __restrict__ ald,
                                                   int nrows, int cols, int stride) {
  __shared__ short A_lds[64 * 136];
  __shared__ float sscale[128];
  __shared__ float sbias[128];
  __shared__ float sasrc[128];
  __shared__ float sadst[128];
  __shared__ float part_s[64][4];
  __shared__ float part_d[64][4];
  int tid = threadIdx.x;
  if (tid < 128) {
    sasrc[tid] = (tid < cols) ? asrc[tid] : 0.f;
    sadst[tid] = (tid < cols) ? adst[tid] : 0.f;
  }
  if (NORM && tid < 128) {
    float s = 0.f, s2 = 0.f;
#pragma unroll 4
    for (int sl = 0; sl < NSLICE; ++sl) {
      s += stats[sl * 256 + tid];
      s2 += stats[sl * 256 + 128 + tid];
    }
    float invn = 1.0f / (float)nrows;
    float mean = s * invn;
    float var = s2 * invn - mean * mean;
    float sc = g[tid] * rsqrtf(var + 1e-5f);
    sscale[tid] = sc;
    sbias[tid] = beta[tid] - mean * sc;
  }
  if (NORM) __syncthreads();
  int row0 = blockIdx.x * 64;
#pragma unroll
  for (int it = 0; it < 8; ++it) {
    int e = (tid + it * 256) * 4;
    int row = e >> 7;
    int kh = e & 127;
    int gr = row0 + row;
    uint2 pk;
    if (NORM) {
      // bf16 input (agg): uint2 = 4 bf16 dims
      u32x2 uv = {0u, 0u};
      if (gr < nrows)
        uv = __builtin_nontemporal_load(
            (const u32x2*)((const uint32_t*)X + (size_t)gr * 64 + (kh >> 1)));
      f32x2 p0 = up2(uv[0]);
      f32x2 p1 = up2(uv[1]);
      float v0 = fmaxf(fmaf(p0.x, sscale[kh + 0], sbias[kh + 0]), 0.f);
      float v1 = fmaxf(fmaf(p0.y, sscale[kh + 1], sbias[kh + 1]), 0.f);
      float v2 = fmaxf(fmaf(p1.x, sscale[kh + 2], sbias[kh + 2]), 0.f);
      float v3 = fmaxf(fmaf(p1.y, sscale[kh + 3], sbias[kh + 3]), 0.f);
      pk.x = bf16x2_pack(v0, v1);
      pk.y = bf16x2_pack(v2, v3);
    } else {
      f32x4v xv = {0.f, 0.f, 0.f, 0.f};
      if (gr < nrows)
        xv = __builtin_nontemporal_load((const f32x4v*)(X + (size_t)gr * 128 + kh));
      pk.x = bf16x2_pack(xv[0], xv[1]);
      pk.y = bf16x2_pack(xv[2], xv[3]);
    }
    *(uint2*)(&A_lds[row * 136 + kh]) = pk;
  }
  __syncthreads();

  int wave = tid >> 6;
  int lane = tid & 63;
  int m = lane & 15;
  int quad = lane >> 4;

  bf16x8v afrag[4];
#pragma unroll
  for (int kc = 0; kc < 4; ++kc)
    afrag[kc] = *(const bf16x8v*)(&A_lds[(wave * 16 + m) * 136 + kc * 32 + quad * 8]);

  f32x4v acc[NT];
#pragma unroll
  for (int t = 0; t < NT; ++t) acc[t] = (f32x4v){0.f, 0.f, 0.f, 0.f};

#pragma unroll
  for (int t = 0; t < NT; ++t) {
#pragma unroll
    for (int kc = 0; kc < 4; ++kc) {
      bf16x8v bfrag = *(const bf16x8v*)(WT + ((t * 16 + m) * 128 + kc * 32 + quad * 8));
      acc[t] = __builtin_amdgcn_mfma_f32_16x16x32_bf16(afrag[kc], bfrag, acc[t], 0, 0, 0);
    }
  }

  // ---- stage H (bf16) into LDS: reuse A_lds ----
  __syncthreads();
  if (NT == 3) {
    // zero cols 48..63 so the readback rows and als chunk-1 are clean
    for (int i = tid; i < 64 * 16; i += 256) {
      int row = i >> 4, c = 48 + (i & 15);
      A_lds[row * 136 + c] = 0;
    }
  }
#pragma unroll
  for (int t = 0; t < NT; ++t) {
    int col = t * 16 + m;
#pragma unroll
    for (int r = 0; r < 4; ++r) {
      int row = wave * 16 + quad * 4 + r;
      A_lds[row * 136 + col] = (short)bf16_1(acc[t][r]);
    }
  }
  __syncthreads();

  // ---- als/ald: 32-col chunk partials, NCH chunks per row ----
  constexpr int NCH = (NT == 8) ? 4 : 2;
  if (tid < 64 * NCH) {
    int row = tid / NCH, ch = tid % NCH;
    float ps = 0.f, pd = 0.f;
#pragma unroll
    for (int q = 0; q < 4; ++q) {
      bf16x8v hv = *(const bf16x8v*)(&A_lds[row * 136 + ch * 32 + q * 8]);
#pragma unroll
      for (int e = 0; e < 8; ++e) {
        float hf = __uint_as_float(((uint32_t)(unsigned short)hv[e]) << 16);
        int c = ch * 32 + q * 8 + e;
        ps = fmaf(hf, sasrc[c], ps);
        pd = fmaf(hf, sadst[c], pd);
      }
    }
    part_s[row][ch] = ps;
    part_d[row][ch] = pd;
  }

  // ---- coalesced H stores (uint4 = 8 cols) ----
  int c8 = stride >> 3;
  int total = 64 * c8;
  for (int idx = tid; idx < total; idx += 256) {
    int row = idx / c8;
    int cc = (idx - row * c8) * 8;
    int grow = row0 + row;
    if (grow < nrows) {
      u32x4 v = *(const u32x4*)(&A_lds[row * 136 + cc]);
      *(u32x4*)(Hout + (size_t)grow * stride + cc) = v;
    }
  }

  __syncthreads();
  if (tid < 64) {
    int grow = row0 + tid;
    if (grow < nrows) {
      if (HEADS == 2) {
        float s0 = part_s[tid][0] + part_s[tid][1];
        float s1 = part_s[tid][2] + part_s[tid][3];
        float d0 = part_d[tid][0] + part_d[tid][1];
        float d1 = part_d[tid][2] + part_d[tid][3];
        ((float2*)als)[grow] = make_float2(s0, s1);
        ((float2*)ald)[grow] = make_float2(d0, d1);
      } else {
        als[grow] = part_s[tid][0] + part_s[tid][1];
        ald[grow] = part_d[tid][0] + part_d[tid][1];
      }
    }
  }
}

// 2 heads x 64 dims, h bf16 (row = 256B = 16 uint4).
// One wave per node; 16 lanes per edge-row, 4 slots. Main loop: 16 edges/iter
// unclamped + clamped 8-edge tail. Output agg written as bf16 (uint4/lane).
// BN partial stats from f32 registers via per-wave LDS row + one atomic pass.
__global__ __launch_bounds__(256) void gat_gather2_k(const int* __restrict__ rowptr,
                                                     const int* __restrict__ csr_src,
                                                     const float* __restrict__ als,
                                                     const float* __restrict__ ald,
                                                     const uint16_t* __restrict__ H,
                                                     const float* __restrict__ bias,
                                                     uint32_t* __restrict__ out,
                                                     float* __restrict__ stats, int N) {
  __shared__ float red[4][256];
  int tid = threadIdx.x;
  int wv = tid >> 6;
  int n = blockIdx.x * 4 + wv;
  int lane = tid & 63;
  int slot = lane >> 4;        // 0..3: edge slot
  int sub = lane & 15;         // uint4 index within row (dims 8*sub..8*sub+7)
  int head = sub >> 3;
  bool alive = n < N;
  int start = 0, end = 0;
  float aldn = 0.f;
  if (alive) {
    start = rowptr[n];
    end = rowptr[n + 1];
    aldn = ald[2 * n + head];
  }
  const char* hbase = (const char*)H;
  uint32_t suboff = (uint32_t)sub << 4;
  bool dlane = (sub & 7) == 0;
  f32x2 acc0 = {0.f, 0.f}, acc1 = {0.f, 0.f}, acc2 = {0.f, 0.f}, acc3 = {0.f, 0.f};
  float dsum = 0.f;
  int j = start;
  // full 16-edge blocks: no clamping, no predication
  for (; j + 16 <= end; j += 16) {
    int e0 = j + slot;
    int s0 = __builtin_nontemporal_load(csr_src + e0);
    int s1 = __builtin_nontemporal_load(csr_src + e0 + 4);
    int s2 = __builtin_nontemporal_load(csr_src + e0 + 8);
    int s3 = __builtin_nontemporal_load(csr_src + e0 + 12);
    uint4 u0 = *(const uint4*)(hbase + (((uint32_t)s0 << 8) + suboff));
    uint4 u1 = *(const uint4*)(hbase + (((uint32_t)s1 << 8) + suboff));
    uint4 u2 = *(const uint4*)(hbase + (((uint32_t)s2 << 8) + suboff));
    uint4 u3 = *(const uint4*)(hbase + (((uint32_t)s3 << 8) + suboff));
    float l0 = als[2 * s0 + head] + aldn;
    float l1 = als[2 * s1 + head] + aldn;
    float l2 = als[2 * s2 + head] + aldn;
    float l3 = als[2 * s3 + head] + aldn;
    l0 = fmaxf(l0, 0.2f * l0);
    l1 = fmaxf(l1, 0.2f * l1);
    l2 = fmaxf(l2, 0.2f * l2);
    l3 = fmaxf(l3, 0.2f * l3);
    float w0 = __expf(l0), w1 = __expf(l1), w2 = __expf(l2), w3 = __expf(l3);
    if (dlane) dsum += (w0 + w1) + (w2 + w3);
    acc0 += up2(u0.x) * w0;
    acc1 += up2(u0.y) * w0;
    acc2 += up2(u0.z) * w0;
    acc3 += up2(u0.w) * w0;
    acc0 += up2(u1.x) * w1;
    acc1 += up2(u1.y) * w1;
    acc2 += up2(u1.z) * w1;
    acc3 += up2(u1.w) * w1;
    acc0 += up2(u2.x) * w2;
    acc1 += up2(u2.y) * w2;
    acc2 += up2(u2.z) * w2;
    acc3 += up2(u2.w) * w2;
    acc0 += up2(u3.x) * w3;
    acc1 += up2(u3.y) * w3;
    acc2 += up2(u3.z) * w3;
    acc3 += up2(u3.w) * w3;
  }
  // clamped tail (up to 15 edges)
  for (; j < end; j += 8) {
    int last = end - 1;
    int ea = j + slot;
    int eb = ea + 4;
    int sa = csr_src[min(ea, last)];
    int sb = csr_src[min(eb, last)];
    uint4 ua = *(const uint4*)(hbase + (((uint32_t)sa << 8) + suboff));
    uint4 ub = *(const uint4*)(hbase + (((uint32_t)sb << 8) + suboff));
    float la = als[2 * sa + head] + aldn;
    float lb = als[2 * sb + head] + aldn;
    la = fmaxf(la, 0.2f * la);
    lb = fmaxf(lb, 0.2f * lb);
    float wa = (ea < end) ? __expf(la) : 0.f;
    float wb = (eb < end) ? __expf(lb) : 0.f;
    if (dlane) dsum += wa + wb;
    acc0 += up2(ua.x) * wa;
    acc1 += up2(ua.y) * wa;
    acc2 += up2(ua.z) * wa;
    acc3 += up2(ua.w) * wa;
    acc0 += up2(ub.x) * wb;
    acc1 += up2(ub.y) * wb;
    acc2 += up2(ub.z) * wb;
    acc3 += up2(ub.w) * wb;
  }
  // combine the 4 slots
  acc0.x += __shfl_xor(acc0.x, 16, 64); acc0.x += __shfl_xor(acc0.x, 32, 64);
  acc0.y += __shfl_xor(acc0.y, 16, 64); acc0.y += __shfl_xor(acc0.y, 32, 64);
  acc1.x += __shfl_xor(acc1.x, 16, 64); acc1.x += __shfl_xor(acc1.x, 32, 64);
  acc1.y += __shfl_xor(acc1.y, 16, 64); acc1.y += __shfl_xor(acc1.y, 32, 64);
  acc2.x += __shfl_xor(acc2.x, 16, 64); acc2.x += __shfl_xor(acc2.x, 32, 64);
  acc2.y += __shfl_xor(acc2.y, 16, 64); acc2.y += __shfl_xor(acc2.y, 32, 64);
  acc3.x += __shfl_xor(acc3.x, 16, 64); acc3.x += __shfl_xor(acc3.x, 32, 64);
  acc3.y += __shfl_xor(acc3.y, 16, 64); acc3.y += __shfl_xor(acc3.y, 32, 64);
  dsum += __shfl_xor(dsum, 16, 64);
  dsum += __shfl_xor(dsum, 32, 64);
  float denom = __shfl(dsum, head << 3, 64);
  float inv = 1.0f / (denom + 1e-16f);
  if (slot == 0) {
    float4 b0 = ((const float4*)bias)[2 * sub];
    float4 b1 = ((const float4*)bias)[2 * sub + 1];
    f32x4v o0, o1;
    o0[0] = acc0.x * inv + b0.x;
    o0[1] = acc0.y * inv + b0.y;
    o0[2] = acc1.x * inv + b0.z;
    o0[3] = acc1.y * inv + b0.w;
    o1[0] = acc2.x * inv + b1.x;
    o1[1] = acc2.y * inv + b1.y;
    o1[2] = acc3.x * inv + b1.z;
    o1[3] = acc3.y * inv + b1.w;
    if (alive) {
      u32x4 pk;
      pk[0] = bf16x2_pack(o0[0], o0[1]);
      pk[1] = bf16x2_pack(o0[2], o0[3]);
      pk[2] = bf16x2_pack(o1[0], o1[1]);
      pk[3] = bf16x2_pack(o1[2], o1[3]);
      __builtin_nontemporal_store(pk, (u32x4*)(out + (size_t)n * 64 + 4 * sub));
    }
    float z = alive ? 1.f : 0.f;
    int c = sub << 3;
    red[wv][c + 0] = o0[0] * z;  red[wv][128 + c + 0] = o0[0] * o0[0] * z;
    red[wv][c + 1] = o0[1] * z;  red[wv][128 + c + 1] = o0[1] * o0[1] * z;
    red[wv][c + 2] = o0[2] * z;  red[wv][128 + c + 2] = o0[2] * o0[2] * z;
    red[wv][c + 3] = o0[3] * z;  red[wv][128 + c + 3] = o0[3] * o0[3] * z;
    red[wv][c + 4] = o1[0] * z;  red[wv][128 + c + 4] = o1[0] * o1[0] * z;
    red[wv][c + 5] = o1[1] * z;  red[wv][128 + c + 5] = o1[1] * o1[1] * z;
    red[wv][c + 6] = o1[2] * z;  red[wv][128 + c + 6] = o1[2] * o1[2] * z;
    red[wv][c + 7] = o1[3] * z;  red[wv][128 + c + 7] = o1[3] * o1[3] * z;
  }
  __syncthreads();
  float v = red[0][tid] + red[1][tid] + red[2][tid] + red[3][tid];
  atomicAdd(&stats[((blockIdx.x & (NSLICE - 1)) << 8) + tid], v);
}

// 1 head x 40 dims, h bf16 padded to 128B rows (5 uint4 used). 5 lanes per
// edge-row, 12 slots (lanes 60-63 idle). Unclamped 12-edge main loop
// (granularity matches mean degree 16) + clamped 12-edge tail.
__global__ __launch_bounds__(256) void gat_gather1_k(const int* __restrict__ rowptr,
                                                     const int* __restrict__ csr_src,
                                                     const float* __restrict__ als,
                                                     const float* __restrict__ ald,
                                                     const uint16_t* __restrict__ H,
                                                     const float* __restrict__ bias,
                                                     float* __restrict__ out, int N) {
  int n = blockIdx.x * 4 + (threadIdx.x >> 6);
  if (n >= N) return;
  int lane = threadIdx.x & 63;
  int slot = lane / 5;            // 0..11 active, 12 = idle (lanes 60-63)
  int d = lane - slot * 5;        // uint4 index within row (dims 8d..8d+7)
  bool act = slot < 12;
  int start = rowptr[n], end = rowptr[n + 1];
  float aldn = ald[n];
  const char* hbase = (const char*)H;
  uint32_t doff = (uint32_t)d << 4;
  f32x2 a0 = {0.f, 0.f}, a1 = {0.f, 0.f}, a2 = {0.f, 0.f}, a3 = {0.f, 0.f};
  float dsum = 0.f;
  int j = start;
  // unclamped main: active lanes always in-range; idle lanes read the
  // zero-padded csr_src[end..] (safe) with w forced 0.
  for (; j + 12 <= end; j += 12) {
    int e0 = j + slot;
    int s0 = __builtin_nontemporal_load(csr_src + e0);
    uint4 u0 = *(const uint4*)(hbase + (((uint32_t)s0 << 7) + doff));
    float l0 = als[s0] + aldn;
    l0 = fmaxf(l0, 0.2f * l0);
    float w0 = act ? __expf(l0) : 0.f;
    if (d == 0) dsum += w0;
    a0 += up2(u0.x) * w0;
    a1 += up2(u0.y) * w0;
    a2 += up2(u0.z) * w0;
    a3 += up2(u0.w) * w0;
  }
  // clamped tail (up to 11 edges)
  for (; j < end; j += 12) {
    int last = end - 1;
    int e0 = j + slot;
    int s0 = __builtin_nontemporal_load(csr_src + min(e0, last));
    uint4 u0 = *(const uint4*)(hbase + (((uint32_t)s0 << 7) + doff));
    float l0 = als[s0] + aldn;
    l0 = fmaxf(l0, 0.2f * l0);
    float w0 = (act && e0 < end) ? __expf(l0) : 0.f;
    if (d == 0) dsum += w0;
    a0 += up2(u0.x) * w0;
    a1 += up2(u0.y) * w0;
    a2 += up2(u0.z) * w0;
    a3 += up2(u0.w) * w0;
  }
  // fold 12 slots -> 1 (same d): +6 slots, +3 slots, then +1,+2 slots
#define FOLD2(off)                                        \
  a0.x += __shfl(a0.x, (lane + off) & 63, 64);            \
  a0.y += __shfl(a0.y, (lane + off) & 63, 64);            \
  a1.x += __shfl(a1.x, (lane + off) & 63, 64);            \
  a1.y += __shfl(a1.y, (lane + off) & 63, 64);            \
  a2.x += __shfl(a2.x, (lane + off) & 63, 64);            \
  a2.y += __shfl(a2.y, (lane + off) & 63, 64);            \
  a3.x += __shfl(a3.x, (lane + off) & 63, 64);            \
  a3.y += __shfl(a3.y, (lane + off) & 63, 64);
  FOLD2(30)  // slots 0..5 += slots 6..11
  FOLD2(15)  // slots 0..2 += slots 3..5
  {
    float t;
    t = __shfl(a0.x, (lane + 5) & 63, 64) + __shfl(a0.x, (lane + 10) & 63, 64); a0.x += t;
    t = __shfl(a0.y, (lane + 5) & 63, 64) + __shfl(a0.y, (lane + 10) & 63, 64); a0.y += t;
    t = __shfl(a1.x, (lane + 5) & 63, 64) + __shfl(a1.x, (lane + 10) & 63, 64); a1.x += t;
    t = __shfl(a1.y, (lane + 5) & 63, 64) + __shfl(a1.y, (lane + 10) & 63, 64); a1.y += t;
    t = __shfl(a2.x, (lane + 5) & 63, 64) + __shfl(a2.x, (lane + 10) & 63, 64); a2.x += t;
    t = __shfl(a2.y, (lane + 5) & 63, 64) + __shfl(a2.y, (lane + 10) & 63, 64); a2.y += t;
    t = __shfl(a3.x, (lane + 5) & 63, 64) + __shfl(a3.x, (lane + 10) & 63, 64); a3.x += t;
    t = __shfl(a3.y, (lane + 5) & 63, 64) + __shfl(a3.y, (lane + 10) & 63, 64); a3.y += t;
  }
#undef FOLD2
#pragma unroll
  for (int off = 1; off < 64; off <<= 1) dsum += __shfl_xor(dsum, off, 64);
  if (lane < 5) {
    float inv = 1.0f / (dsum + 1e-16f);
    float4 b4a = ((const float4*)bias)[2 * d];
    float4 b4b = ((const float4*)bias)[2 * d + 1];
    f32x4v o0, o1;
    o0[0] = a0.x * inv + b4a.x;
    o0[1] = a0.y * inv + b4a.y;
    o0[2] = a1.x * inv + b4a.z;
    o0[3] = a1.y * inv + b4a.w;
    o1[0] = a2.x * inv + b4b.x;
    o1[1] = a2.y * inv + b4b.y;
    o1[2] = a3.x * inv + b4b.z;
    o1[3] = a3.y * inv + b4b.w;
    float* orow = out + (size_t)n * 40 + 8 * d;
    __builtin_nontemporal_store(o0, (f32x4v*)orow);
    __builtin_nontemporal_store(o1, (f32x4v*)(orow + 4));
  }
}

extern "C" void kernel_launch(void* const* d_in, const int* in_sizes, int n_in,
                              void* d_out, int out_size, void* d_ws, size_t ws_size,
                              hipStream_t stream) {
  const float* x     = (const float*)d_in[0];
  const int*   ei    = (const int*)d_in[1];
  const float* w0    = (const float*)d_in[2];
  const float* asrc0 = (const float*)d_in[3];
  const float* adst0 = (const float*)d_in[4];
  const float* b0    = (const float*)d_in[5];
  const float* g0    = (const float*)d_in[6];
  const float* beta0 = (const float*)d_in[7];
  const float* w1    = (const float*)d_in[8];
  const float* asrc1 = (const float*)d_in[9];
  const float* adst1 = (const float*)d_in[10];
  const float* b1    = (const float*)d_in[11];
  const float* g1    = (const float*)d_in[12];
  const float* beta1 = (const float*)d_in[13];
  const float* w2    = (const float*)d_in[14];
  const float* asrc2 = (const float*)d_in[15];
  const float* adst2 = (const float*)d_in[16];
  const float* b2    = (const float*)d_in[17];

  const int N = in_sizes[0] / 128;   // 100000
  const int E = in_sizes[1] / 2;     // 1600000

  const int nbuck = (N + 511) >> 9;              // 196
  const int nbA = (E + TILE_A - 1) / TILE_A;     // 196

  char* p = (char*)d_ws;
  auto carve = [&](size_t bytes) {
    char* q = p;
    p += (bytes + 255) & ~(size_t)255;
    return q;
  };
  int*      counts  = (int*)carve((size_t)MPAD * 4);      // padded for reg-scan
  int*      rowptr  = (int*)carve((size_t)(N + 1) * 4);
  uint32_t* barr    = (uint32_t*)carve((size_t)E * 4);
  int*      csr_src = (int*)carve((size_t)(E + 64) * 4);  // +64 pad (zeroed)
  float*    als     = (float*)carve((size_t)N * 2 * 4);
  float*    ald     = (float*)carve((size_t)N * 2 * 4);
  float*    stats   = (float*)carve((size_t)2 * NSLICE * 256 * 4);
  uint16_t* wt0     = (uint16_t*)carve(128 * 128 * 2);
  uint16_t* wt1     = (uint16_t*)carve(128 * 128 * 2);
  uint16_t* wt2     = (uint16_t*)carve(48 * 128 * 2);
  uint16_t* hbuf    = (uint16_t*)carve((size_t)N * 128 * 2);  // bf16
  uint32_t* agg     = (uint32_t*)carve((size_t)N * 64 * 4);   // bf16 x2 packed

  float* stats0 = stats;
  float* stats1 = stats + NSLICE * 256;

  const int* esrc = ei;
  const int* edst = ei + E;

  // ---- CSR by dst (fully sorted; shared across all 3 layers) ----
  // hist also does weight transposes + stats zeroing + counts-pad zeroing.
  bucket_hist_k<<<nbA, 256, 0, stream>>>(edst, counts, E, nbA, nbuck,
                                         w0, w1, w2, wt0, wt1, wt2, stats);
  scan_counts_k<<<1, 1024, 0, stream>>>(counts, rowptr, csr_src, N, E);
  bucket_scatter_k<<<nbA, 256, 0, stream>>>(esrc, edst, counts, barr, E, nbA, nbuck);
  bucket_sort_k<<<nbuck, 256, 0, stream>>>(barr, counts, rowptr, csr_src, nbA, nbuck, N, E);

  const int gemm_grid = (N + 63) / 64;
  const int node_grid = (N + 3) / 4;

  // ---- layer 0: GAT(128 -> 64x2) -> (BN+ReLU fused into next gemm) ----
  gemm_mfma_k<false, 8, 2><<<gemm_grid, 256, 0, stream>>>(x, wt0, hbuf, nullptr, nullptr,
                                                          nullptr, asrc0, adst0, als, ald,
                                                          N, 128, 128);
  gat_gather2_k<<<node_grid, 256, 0, stream>>>(rowptr, csr_src, als, ald, hbuf,
                                               b0, agg, stats0, N);

  // ---- layer 1 ----
  gemm_mfma_k<true, 8, 2><<<gemm_grid, 256, 0, stream>>>((const float*)agg, wt1, hbuf,
                                                         stats0, g0, beta0,
                                                         asrc1, adst1, als, ald, N, 128, 128);
  gat_gather2_k<<<node_grid, 256, 0, stream>>>(rowptr, csr_src, als, ald, hbuf,
                                               b1, agg, stats1, N);

  // ---- layer 2: GAT(128 -> 40, heads=1) -> d_out (H rows padded to 128B) ----
  gemm_mfma_k<true, 3, 1><<<gemm_grid, 256, 0, stream>>>((const float*)agg, wt2, hbuf,
                                                         stats1, g1, beta1,
                                                         asrc2, adst2, als, ald, N, 40, 64);
  gat_gather1_k<<<node_grid, 256, 0, stream>>>(rowptr, csr_src, als, ald, hbuf,
                                               b2, (float*)d_out, N);
}